// Round 12
// baseline (93.742 us; speedup 1.0000x reference)
//
#include <hip/hip_runtime.h>
#include <hip/hip_bf16.h>

// LSTM cell fused: C = [x|h] @ [Wx|Wh]^T (gate-per-16col-fragment N layout).
// GEMM M=4096, N=4096, K=2048.
// R12: 2 blocks/CU TLP (R11) + 3-slot LDS ring, BK=32 (24 KB/slot, 72 KB
// total, 2 blocks fit). Stage t+2 while computing t; counted
// vmcnt(3)+lgkmcnt(0) + ONE barrier per tile -> no intra-block stage stall;
// co-resident block covers the rest. 2-way-free swizzle for 64 B rows.

constexpr int Mdim = 4096;
constexpr int Ndim = 4096;
constexpr int Kdim = 2048;
constexpr int Hdim = 1024;
constexpr int BM = 128;
constexpr int BN = 256;
constexpr int BK = 32;
constexpr int NT = Kdim / BK;   // 64 K-tiles

using short8 = __attribute__((ext_vector_type(8))) short;
using f32x4  = __attribute__((ext_vector_type(4))) float;

__device__ __forceinline__ float sigmoid_(float x) {
    return 1.f / (1.f + __expf(-x));
}
__device__ __forceinline__ float tanh_(float x) {
    float e = __expf(2.f * x);
    return (e - 1.f) / (e + 1.f);
}

// ---- merged builds: blocks [0,4096) build A = [x|h]; [4096,8192) build B ----
__global__ void build_AB(const float* __restrict__ x, const float* __restrict__ h,
                         const float* __restrict__ Wxi, const float* __restrict__ Whi,
                         const float* __restrict__ Wxf, const float* __restrict__ Whf,
                         const float* __restrict__ Wxg, const float* __restrict__ Whg,
                         const float* __restrict__ Wxo, const float* __restrict__ Who,
                         __hip_bfloat16* __restrict__ A, __hip_bfloat16* __restrict__ B) {
    int bidx = blockIdx.x;
    const float* src;
    __hip_bfloat16* dst;
    int idx = (bidx & 4095) * 256 + threadIdx.x;
    int row = idx >> 8;
    int c8  = (idx & 255) * 8;
    if (bidx < 4096) {
        src = (c8 < 1024) ? (x + (size_t)row * 1024 + c8)
                          : (h + (size_t)row * 1024 + (c8 - 1024));
        dst = A + (size_t)row * Kdim + c8;
    } else {
        int g = (row >> 4) & 3;
        int j = ((row >> 6) << 4) | (row & 15);
        const float* Wx = (g == 0) ? Wxi : (g == 1) ? Wxf : (g == 2) ? Wxg : Wxo;
        const float* Wh = (g == 0) ? Whi : (g == 1) ? Whf : (g == 2) ? Whg : Who;
        src = (c8 < 1024) ? (Wx + (size_t)j * 1024 + c8)
                          : (Wh + (size_t)j * 1024 + (c8 - 1024));
        dst = B + (size_t)row * Kdim + c8;
    }
    float4 f0 = ((const float4*)src)[0];
    float4 f1 = ((const float4*)src)[1];
    union { short8 v; __hip_bfloat16 e[8]; } u;
    u.e[0] = __float2bfloat16(f0.x); u.e[1] = __float2bfloat16(f0.y);
    u.e[2] = __float2bfloat16(f0.z); u.e[3] = __float2bfloat16(f0.w);
    u.e[4] = __float2bfloat16(f1.x); u.e[5] = __float2bfloat16(f1.y);
    u.e[6] = __float2bfloat16(f1.z); u.e[7] = __float2bfloat16(f1.w);
    *(short8*)dst = u.v;
}

#define RD(p) (*(const short8*)(p))

// ---- fused GEMM + LSTM epilogue: 3-slot ring, 2 blocks/CU ----
__launch_bounds__(512, 4)
__global__ void lstm_gemm(const __hip_bfloat16* __restrict__ A,
                          const __hip_bfloat16* __restrict__ B,
                          const float* __restrict__ c_prev,
                          const float* __restrict__ b_i, const float* __restrict__ b_f,
                          const float* __restrict__ b_g, const float* __restrict__ b_o,
                          float* __restrict__ out_h, float* __restrict__ out_c) {
    // [slot][region: 0=A(128x32), 1=B rows 0-127, 2=B rows 128-255] = 72 KB
    __shared__ __hip_bfloat16 lds[3][3][128 * 32];

    const int tid  = threadIdx.x;
    const int lane = tid & 63;
    const int w    = tid >> 6;          // 0..7
    const int wr   = w >> 2;            // 0..1 (M half: 64 rows)
    const int wc   = w & 3;             // 0..3 (N quarter: 64 cols)
    const int l15  = lane & 15, lhi = lane >> 4;

    // XCD-aware swizzle (nwg = 512, divisible by 8)
    int bid = blockIdx.x;
    int swz = (bid & 7) * 64 + (bid >> 3);
    const int bm = (swz >> 4) * BM;
    const int bn = (swz & 15) * BN;

    // Staging: each gll = 8 KB = 128 rows x 64 B. Dest linear tid*16
    // (row = tid>>2, phys chunk = tid&3). Source chunk pre-permuted:
    // c_src = (tid&3) ^ ((row>>1)&3) = (tid&3) ^ ((tid>>3)&3).
    const int srow_  = tid >> 2;                                  // 0..127
    const int schunk = ((tid & 3) ^ ((tid >> 3) & 3)) * 8;        // col element

    // ds_read: byte-in-row = (lhi ^ ((row>>1)&3))<<4 ; (row>>1)&3 == (l15>>1)&3
    const int koff = ((lhi ^ ((l15 >> 1) & 3)) << 4);
    const int offA = (wr * 64 + l15) * 64 + koff;
    const int offB = (wc >> 1) * 8192 + ((wc & 1) * 64 + l15) * 64 + koff;

#define STG1(dstbase, srcptr, grow, kcol)                                       \
    __builtin_amdgcn_global_load_lds(                                           \
        (const __attribute__((address_space(1))) unsigned*)(                    \
            (srcptr) + (size_t)((grow) + srow_) * Kdim + (kcol) + schunk),      \
        (__attribute__((address_space(3))) unsigned*)(                          \
            (char*)(dstbase) + tid * 16), 16, 0, 0)

#define STAGE_TILE(s, kc)                                                       \
    do {                                                                        \
        STG1(&lds[s][0][0], A, bm + 0,   kc);                                   \
        STG1(&lds[s][1][0], B, bn + 0,   kc);                                   \
        STG1(&lds[s][2][0], B, bn + 128, kc);                                   \
    } while (0)

    f32x4 acc[4][4];
#pragma unroll
    for (int a = 0; a < 4; ++a)
#pragma unroll
        for (int b = 0; b < 4; ++b)
            acc[a][b] = (f32x4){0.f, 0.f, 0.f, 0.f};

    // ---- prologue: stage tiles 0,1 into slots 0,1; wait slot 0 ----
    STAGE_TILE(0, 0);
    STAGE_TILE(1, BK);
    asm volatile("s_waitcnt vmcnt(3)" ::: "memory");   // slot 0 landed
    __builtin_amdgcn_s_barrier();

    // one K-tile: stage slot sW_ (tile t+2), read slot sR_, 16 MFMA,
    // counted wait + single barrier.
#define BODY(t_, sR_, sW_)                                                      \
    do {                                                                        \
        if ((t_) + 2 < NT) STAGE_TILE(sW_, ((t_) + 2) * BK);                    \
        const char* Ab = (const char*)&lds[sR_][0][0] + offA;                   \
        const char* Bb = (const char*)&lds[sR_][1][0] + offB;                   \
        short8 af[4], bf[4];                                                    \
        _Pragma("unroll")                                                       \
        for (int a = 0; a < 4; ++a) af[a] = RD(Ab + a * 1024);                  \
        _Pragma("unroll")                                                       \
        for (int b = 0; b < 4; ++b) bf[b] = RD(Bb + b * 1024);                  \
        __builtin_amdgcn_s_setprio(1);                                          \
        _Pragma("unroll")                                                       \
        for (int a = 0; a < 4; ++a)                                             \
            _Pragma("unroll")                                                   \
            for (int b = 0; b < 4; ++b)                                         \
                acc[a][b] = __builtin_amdgcn_mfma_f32_16x16x32_bf16(            \
                    af[a], bf[b], acc[a][b], 0, 0, 0);                          \
        __builtin_amdgcn_s_setprio(0);                                          \
        if ((t_) + 1 < NT) {                                                    \
            __builtin_amdgcn_sched_barrier(0);                                  \
            if ((t_) + 2 < NT)                                                  \
                asm volatile("s_waitcnt vmcnt(3) lgkmcnt(0)" ::: "memory");     \
            else                                                                \
                asm volatile("s_waitcnt vmcnt(0) lgkmcnt(0)" ::: "memory");     \
            __builtin_amdgcn_s_barrier();                                       \
        }                                                                       \
    } while (0)

    for (int t3 = 0; t3 < NT - 1; t3 += 3) {   // 21 triples: t = 0..62
        BODY(t3 + 0, 0, 2);
        BODY(t3 + 1, 1, 0);
        BODY(t3 + 2, 2, 1);
    }
    BODY(NT - 1, 0, 2);                         // t = 63 (63 % 3 == 0)
#undef STG1
#undef STAGE_TILE
#undef BODY

    // ---- fused LSTM epilogue (shuffle-free) ----
    const int j0 = ((bn + wc * 64) >> 6) * 16 + l15;
    const float bi  = b_i[j0];
    const float bf_ = b_f[j0];
    const float bg  = b_g[j0];
    const float bo  = b_o[j0];

#pragma unroll
    for (int a = 0; a < 4; ++a) {
        int mbase = bm + wr * 64 + a * 16 + lhi * 4;
#pragma unroll
        for (int r = 0; r < 4; ++r) {
            int m = mbase + r;
            float vi = acc[a][0][r] + bi;
            float vf = acc[a][1][r] + bf_;
            float vg = acc[a][2][r] + bg;
            float vo = acc[a][3][r] + bo;
            float it = sigmoid_(vi);
            float ft = sigmoid_(vf);
            float gt = tanh_(vg);
            float ot = sigmoid_(vo);
            float cp = c_prev[(size_t)m * Hdim + j0];
            float ct = ft * cp + it * gt;
            float ht = ot * tanh_(ct);
            out_h[(size_t)m * Hdim + j0] = ht;
            out_c[(size_t)m * Hdim + j0] = ct;
        }
    }
}

extern "C" void kernel_launch(void* const* d_in, const int* in_sizes, int n_in,
                              void* d_out, int out_size, void* d_ws, size_t ws_size,
                              hipStream_t stream) {
    const float* x_t    = (const float*)d_in[0];
    const float* h_prev = (const float*)d_in[1];
    const float* c_prev = (const float*)d_in[2];
    const float* W_xi   = (const float*)d_in[3];
    const float* W_hi   = (const float*)d_in[4];
    const float* b_i    = (const float*)d_in[5];
    const float* W_xf   = (const float*)d_in[6];
    const float* W_hf   = (const float*)d_in[7];
    const float* b_f    = (const float*)d_in[8];
    const float* W_xg   = (const float*)d_in[9];
    const float* W_hg   = (const float*)d_in[10];
    const float* b_g    = (const float*)d_in[11];
    const float* W_xo   = (const float*)d_in[12];
    const float* W_ho   = (const float*)d_in[13];
    const float* b_o    = (const float*)d_in[14];

    float* out_h = (float*)d_out;
    float* out_c = out_h + (size_t)Mdim * Hdim;

    __hip_bfloat16* Abf = (__hip_bfloat16*)d_ws;
    __hip_bfloat16* Bbf = Abf + (size_t)Mdim * Kdim;

    build_AB<<<8192, 256, 0, stream>>>(x_t, h_prev, W_xi, W_hi, W_xf, W_hf,
                                       W_xg, W_hg, W_xo, W_ho, Abf, Bbf);

    lstm_gemm<<<dim3((Mdim / BM) * (Ndim / BN)), 512, 0, stream>>>(
        Abf, Bbf, c_prev, b_i, b_f, b_g, b_o, out_h, out_c);
}

// Round 13
// 92.505 us; speedup vs baseline: 1.0134x; 1.0134x over previous
//
#include <hip/hip_runtime.h>
#include <hip/hip_bf16.h>

// LSTM cell fused: C = [x|h] @ [Wx|Wh]^T (gate-per-16col-fragment N layout).
// GEMM M=4096, N=4096, K=2048.
// R13: max block-level TLP. 128x128 tile, BK=64, 256 threads (4 waves of
// 64x64), single-buffered LDS 32 KB -> 4 blocks/CU; launch_bounds(256,4)
// (VGPR<=128) -> 16 waves/CU over 4 UNSYNCHRONIZED blocks covering each
// other's stage/drain stalls (R9-R11 diagnosis: gll issue+drain window at
// barrier lockstep is the binder; coverage ratio is the lever).
// BK=64 keeps staged rows = 128 B = HBM line granule (R12 lesson: 64 B rows
// over-fetch 1.7x). Proven 0-conflict XOR swizzle; bijective XCD swizzle.

constexpr int Mdim = 4096;
constexpr int Ndim = 4096;
constexpr int Kdim = 2048;
constexpr int Hdim = 1024;
constexpr int BM = 128;
constexpr int BN = 128;
constexpr int BK = 64;
constexpr int NT = Kdim / BK;   // 32 K-tiles

using short8 = __attribute__((ext_vector_type(8))) short;
using f32x4  = __attribute__((ext_vector_type(4))) float;

__device__ __forceinline__ float sigmoid_(float x) {
    return 1.f / (1.f + __expf(-x));
}
__device__ __forceinline__ float tanh_(float x) {
    float e = __expf(2.f * x);
    return (e - 1.f) / (e + 1.f);
}

// ---- merged builds: blocks [0,4096) build A = [x|h]; [4096,8192) build B ----
__global__ void build_AB(const float* __restrict__ x, const float* __restrict__ h,
                         const float* __restrict__ Wxi, const float* __restrict__ Whi,
                         const float* __restrict__ Wxf, const float* __restrict__ Whf,
                         const float* __restrict__ Wxg, const float* __restrict__ Whg,
                         const float* __restrict__ Wxo, const float* __restrict__ Who,
                         __hip_bfloat16* __restrict__ A, __hip_bfloat16* __restrict__ B) {
    int bidx = blockIdx.x;
    const float* src;
    __hip_bfloat16* dst;
    int idx = (bidx & 4095) * 256 + threadIdx.x;
    int row = idx >> 8;
    int c8  = (idx & 255) * 8;
    if (bidx < 4096) {
        src = (c8 < 1024) ? (x + (size_t)row * 1024 + c8)
                          : (h + (size_t)row * 1024 + (c8 - 1024));
        dst = A + (size_t)row * Kdim + c8;
    } else {
        int g = (row >> 4) & 3;
        int j = ((row >> 6) << 4) | (row & 15);
        const float* Wx = (g == 0) ? Wxi : (g == 1) ? Wxf : (g == 2) ? Wxg : Wxo;
        const float* Wh = (g == 0) ? Whi : (g == 1) ? Whf : (g == 2) ? Whg : Who;
        src = (c8 < 1024) ? (Wx + (size_t)j * 1024 + c8)
                          : (Wh + (size_t)j * 1024 + (c8 - 1024));
        dst = B + (size_t)row * Kdim + c8;
    }
    float4 f0 = ((const float4*)src)[0];
    float4 f1 = ((const float4*)src)[1];
    union { short8 v; __hip_bfloat16 e[8]; } u;
    u.e[0] = __float2bfloat16(f0.x); u.e[1] = __float2bfloat16(f0.y);
    u.e[2] = __float2bfloat16(f0.z); u.e[3] = __float2bfloat16(f0.w);
    u.e[4] = __float2bfloat16(f1.x); u.e[5] = __float2bfloat16(f1.y);
    u.e[6] = __float2bfloat16(f1.z); u.e[7] = __float2bfloat16(f1.w);
    *(short8*)dst = u.v;
}

#define RD(p) (*(const short8*)(p))

// ---- fused GEMM + LSTM epilogue, single-buffer 2-barrier, 4 blocks/CU ----
__launch_bounds__(256, 4)
__global__ void lstm_gemm(const __hip_bfloat16* __restrict__ A,
                          const __hip_bfloat16* __restrict__ B,
                          const float* __restrict__ c_prev,
                          const float* __restrict__ b_i, const float* __restrict__ b_f,
                          const float* __restrict__ b_g, const float* __restrict__ b_o,
                          float* __restrict__ out_h, float* __restrict__ out_c) {
    // A: 128x64 bf16 = 16 KB; B: 128x64 = 16 KB  -> 32 KB/block
    __shared__ __hip_bfloat16 As[128 * 64];
    __shared__ __hip_bfloat16 Bs[128 * 64];

    const int tid  = threadIdx.x;
    const int lane = tid & 63;
    const int w    = tid >> 6;          // 0..3
    const int wr   = w >> 1;            // 0..1 (M half: 64 rows)
    const int wc   = w & 1;             // 0..1 (N half: 64 cols)
    const int l15  = lane & 15, lhi = lane >> 4;

    // XCD-aware swizzle (nwg = 1024, divisible by 8)
    int bid = blockIdx.x;
    int swz = (bid & 7) * 128 + (bid >> 3);
    const int bm = (swz >> 5) * BM;     // 32 M-tiles
    const int bn = (swz & 31) * BN;     // 32 N-tiles

    // Staging: each gll = 4 KB = 32 rows x 128 B. Dest linear tid*16
    // (row = tid>>3 within region, chunk = tid&7). Source chunk pre-permuted
    // with read swizzle: c_src = (tid&7) ^ (row&7), row&7 = (tid>>3)&7.
    const int srow_  = tid >> 3;                                  // 0..31
    const int schunk = ((tid & 7) ^ ((tid >> 3) & 7)) * 8;        // col element

    // ds_read swizzle: byte-in-row = (kk*64 + lhi*16) ^ ((row&7)<<4); row&7==l15&7
    const int swz4 = (l15 & 7) << 4;

#define STG1(dstbase, byteoff, srcptr, grow, kcol)                              \
    __builtin_amdgcn_global_load_lds(                                           \
        (const __attribute__((address_space(1))) unsigned*)(                    \
            (srcptr) + (size_t)((grow) + srow_) * Kdim + (kcol) + schunk),      \
        (__attribute__((address_space(3))) unsigned*)(                          \
            (char*)(dstbase) + (byteoff) + tid * 16), 16, 0, 0)

#define STAGE_TILE(kc)                                                          \
    do {                                                                        \
        STG1(As, 0,     A, bm + 0,  kc);                                        \
        STG1(As, 4096,  A, bm + 32, kc);                                        \
        STG1(As, 8192,  A, bm + 64, kc);                                        \
        STG1(As, 12288, A, bm + 96, kc);                                        \
        STG1(Bs, 0,     B, bn + 0,  kc);                                        \
        STG1(Bs, 4096,  B, bn + 32, kc);                                        \
        STG1(Bs, 8192,  B, bn + 64, kc);                                        \
        STG1(Bs, 12288, B, bn + 96, kc);                                        \
    } while (0)

    f32x4 acc[4][4];
#pragma unroll
    for (int a = 0; a < 4; ++a)
#pragma unroll
        for (int b = 0; b < 4; ++b)
            acc[a][b] = (f32x4){0.f, 0.f, 0.f, 0.f};

    // ---- prologue: stage tile 0, drain ----
    STAGE_TILE(0);
    __builtin_amdgcn_sched_barrier(0);
    asm volatile("s_waitcnt vmcnt(0)" ::: "memory");
    __builtin_amdgcn_s_barrier();

    for (int t = 0; t < NT; ++t) {
        // ---- compute tile t ----
#pragma unroll
        for (int kk = 0; kk < 2; ++kk) {
            const int kof = (kk * 64 + lhi * 16) ^ swz4;
            short8 af[4], bf[4];
#pragma unroll
            for (int a = 0; a < 4; ++a)
                af[a] = RD((const char*)As + (wr * 64 + a * 16 + l15) * 128 + kof);
#pragma unroll
            for (int b = 0; b < 4; ++b)
                bf[b] = RD((const char*)Bs + (wc * 64 + b * 16 + l15) * 128 + kof);
            __builtin_amdgcn_s_setprio(1);
#pragma unroll
            for (int a = 0; a < 4; ++a)
#pragma unroll
                for (int b = 0; b < 4; ++b)
                    acc[a][b] = __builtin_amdgcn_mfma_f32_16x16x32_bf16(
                        af[a], bf[b], acc[a][b], 0, 0, 0);
            __builtin_amdgcn_s_setprio(0);
        }

        if (t + 1 < NT) {
            __builtin_amdgcn_s_barrier();       // all waves' reads of t done
            STAGE_TILE((t + 1) * BK);           // overwrite single buffer
            __builtin_amdgcn_sched_barrier(0);
            asm volatile("s_waitcnt vmcnt(0)" ::: "memory");
            __builtin_amdgcn_s_barrier();       // t+1 visible to all
        }
    }
#undef STG1
#undef STAGE_TILE

    // ---- fused LSTM epilogue (shuffle-free) ----
    const int j0 = ((bn + wc * 64) >> 6) * 16 + l15;
    const float bi  = b_i[j0];
    const float bf_ = b_f[j0];
    const float bg  = b_g[j0];
    const float bo  = b_o[j0];

#pragma unroll
    for (int a = 0; a < 4; ++a) {
        int mbase = bm + wr * 64 + a * 16 + lhi * 4;
#pragma unroll
        for (int r = 0; r < 4; ++r) {
            int m = mbase + r;
            float vi = acc[a][0][r] + bi;
            float vf = acc[a][1][r] + bf_;
            float vg = acc[a][2][r] + bg;
            float vo = acc[a][3][r] + bo;
            float it = sigmoid_(vi);
            float ft = sigmoid_(vf);
            float gt = tanh_(vg);
            float ot = sigmoid_(vo);
            float cp = c_prev[(size_t)m * Hdim + j0];
            float ct = ft * cp + it * gt;
            float ht = ot * tanh_(ct);
            out_h[(size_t)m * Hdim + j0] = ht;
            out_c[(size_t)m * Hdim + j0] = ct;
        }
    }
}

extern "C" void kernel_launch(void* const* d_in, const int* in_sizes, int n_in,
                              void* d_out, int out_size, void* d_ws, size_t ws_size,
                              hipStream_t stream) {
    const float* x_t    = (const float*)d_in[0];
    const float* h_prev = (const float*)d_in[1];
    const float* c_prev = (const float*)d_in[2];
    const float* W_xi   = (const float*)d_in[3];
    const float* W_hi   = (const float*)d_in[4];
    const float* b_i    = (const float*)d_in[5];
    const float* W_xf   = (const float*)d_in[6];
    const float* W_hf   = (const float*)d_in[7];
    const float* b_f    = (const float*)d_in[8];
    const float* W_xg   = (const float*)d_in[9];
    const float* W_hg   = (const float*)d_in[10];
    const float* b_g    = (const float*)d_in[11];
    const float* W_xo   = (const float*)d_in[12];
    const float* W_ho   = (const float*)d_in[13];
    const float* b_o    = (const float*)d_in[14];

    float* out_h = (float*)d_out;
    float* out_c = out_h + (size_t)Mdim * Hdim;

    __hip_bfloat16* Abf = (__hip_bfloat16*)d_ws;
    __hip_bfloat16* Bbf = Abf + (size_t)Mdim * Kdim;

    build_AB<<<8192, 256, 0, stream>>>(x_t, h_prev, W_xi, W_hi, W_xf, W_hf,
                                       W_xg, W_hg, W_xo, W_ho, Abf, Bbf);

    lstm_gemm<<<dim3((Mdim / BM) * (Ndim / BN)), 256, 0, stream>>>(
        Abf, Bbf, c_prev, b_i, b_f, b_g, b_o, out_h, out_c);
}

// Round 14
// 88.932 us; speedup vs baseline: 1.0541x; 1.0402x over previous
//
#include <hip/hip_runtime.h>
#include <hip/hip_bf16.h>

// LSTM cell fused: C = [x|h] @ [Wx|Wh]^T (gate-per-16col-fragment N layout).
// GEMM M=4096, N=4096, K=2048.
// R14 = R11 (128x256, BK=64, 8 waves, single-buffer A, 2 blocks/CU) + B
// double-buffer (80 KB LDS total, still 2 blocks/CU). B(t+1)'s 4 gll are
// issued at tile START and land under the compute phase; only A's 2 gll
// remain inside the serialized BAR1..BAR2 window (R9: gll window ~1400 cyc
// was the binder; this cuts it to ~500).

constexpr int Mdim = 4096;
constexpr int Ndim = 4096;
constexpr int Kdim = 2048;
constexpr int Hdim = 1024;
constexpr int BM = 128;
constexpr int BN = 256;
constexpr int BK = 64;
constexpr int NT = Kdim / BK;   // 32 K-tiles

using short8 = __attribute__((ext_vector_type(8))) short;
using f32x4  = __attribute__((ext_vector_type(4))) float;

__device__ __forceinline__ float sigmoid_(float x) {
    return 1.f / (1.f + __expf(-x));
}
__device__ __forceinline__ float tanh_(float x) {
    float e = __expf(2.f * x);
    return (e - 1.f) / (e + 1.f);
}

// ---- merged builds: blocks [0,4096) build A = [x|h]; [4096,8192) build B ----
__global__ void build_AB(const float* __restrict__ x, const float* __restrict__ h,
                         const float* __restrict__ Wxi, const float* __restrict__ Whi,
                         const float* __restrict__ Wxf, const float* __restrict__ Whf,
                         const float* __restrict__ Wxg, const float* __restrict__ Whg,
                         const float* __restrict__ Wxo, const float* __restrict__ Who,
                         __hip_bfloat16* __restrict__ A, __hip_bfloat16* __restrict__ B) {
    int bidx = blockIdx.x;
    const float* src;
    __hip_bfloat16* dst;
    int idx = (bidx & 4095) * 256 + threadIdx.x;
    int row = idx >> 8;
    int c8  = (idx & 255) * 8;
    if (bidx < 4096) {
        src = (c8 < 1024) ? (x + (size_t)row * 1024 + c8)
                          : (h + (size_t)row * 1024 + (c8 - 1024));
        dst = A + (size_t)row * Kdim + c8;
    } else {
        int g = (row >> 4) & 3;
        int j = ((row >> 6) << 4) | (row & 15);
        const float* Wx = (g == 0) ? Wxi : (g == 1) ? Wxf : (g == 2) ? Wxg : Wxo;
        const float* Wh = (g == 0) ? Whi : (g == 1) ? Whf : (g == 2) ? Whg : Who;
        src = (c8 < 1024) ? (Wx + (size_t)j * 1024 + c8)
                          : (Wh + (size_t)j * 1024 + (c8 - 1024));
        dst = B + (size_t)row * Kdim + c8;
    }
    float4 f0 = ((const float4*)src)[0];
    float4 f1 = ((const float4*)src)[1];
    union { short8 v; __hip_bfloat16 e[8]; } u;
    u.e[0] = __float2bfloat16(f0.x); u.e[1] = __float2bfloat16(f0.y);
    u.e[2] = __float2bfloat16(f0.z); u.e[3] = __float2bfloat16(f0.w);
    u.e[4] = __float2bfloat16(f1.x); u.e[5] = __float2bfloat16(f1.y);
    u.e[6] = __float2bfloat16(f1.z); u.e[7] = __float2bfloat16(f1.w);
    *(short8*)dst = u.v;
}

#define RD(p) (*(const short8*)(p))

// ---- fused GEMM + LSTM epilogue: A single-buffer, B dbuf, 2 blocks/CU ----
__launch_bounds__(512, 4)
__global__ void lstm_gemm(const __hip_bfloat16* __restrict__ A,
                          const __hip_bfloat16* __restrict__ B,
                          const float* __restrict__ c_prev,
                          const float* __restrict__ b_i, const float* __restrict__ b_f,
                          const float* __restrict__ b_g, const float* __restrict__ b_o,
                          float* __restrict__ out_h, float* __restrict__ out_c) {
    __shared__ __hip_bfloat16 As[128 * 64];        // 16 KB
    __shared__ __hip_bfloat16 Bs[2][256 * 64];     // 2 x 32 KB

    const int tid  = threadIdx.x;
    const int lane = tid & 63;
    const int w    = tid >> 6;          // 0..7
    const int wr   = w >> 2;            // 0..1 (M half: 64 rows)
    const int wc   = w & 3;             // 0..3 (N quarter: 64 cols)
    const int l15  = lane & 15, lhi = lane >> 4;

    // XCD-aware swizzle (nwg = 512, divisible by 8)
    int bid = blockIdx.x;
    int swz = (bid & 7) * 64 + (bid >> 3);
    const int bm = (swz >> 4) * BM;
    const int bn = (swz & 15) * BN;

    // Staging: each gll = 8 KB = 64 rows x 128 B; dest linear tid*16.
    // Source chunk pre-permuted with read swizzle: c_src = (tid&7) ^ (row&7).
    const int srow_  = tid >> 3;                                  // 0..63
    const int schunk = ((tid & 7) ^ ((tid >> 3) & 7)) * 8;        // col element

    // ds_read swizzle: byte-in-row = (kk*64 + lhi*16) ^ ((row&7)<<4); row&7==l15&7
    const int swz4 = (l15 & 7) << 4;

#define STG1(dstbase, byteoff, srcptr, grow, kcol)                              \
    __builtin_amdgcn_global_load_lds(                                           \
        (const __attribute__((address_space(1))) unsigned*)(                    \
            (srcptr) + (size_t)((grow) + srow_) * Kdim + (kcol) + schunk),      \
        (__attribute__((address_space(3))) unsigned*)(                          \
            (char*)(dstbase) + (byteoff) + tid * 16), 16, 0, 0)

#define STAGE_B(s, kc)                                                          \
    do {                                                                        \
        STG1(&Bs[s][0], 0,     B, bn + 0,   kc);                                \
        STG1(&Bs[s][0], 8192,  B, bn + 64,  kc);                                \
        STG1(&Bs[s][0], 16384, B, bn + 128, kc);                                \
        STG1(&Bs[s][0], 24576, B, bn + 192, kc);                                \
    } while (0)

#define STAGE_A(kc)                                                             \
    do {                                                                        \
        STG1(As, 0,    A, bm + 0,  kc);                                         \
        STG1(As, 8192, A, bm + 64, kc);                                         \
    } while (0)

    f32x4 acc[4][4];
#pragma unroll
    for (int a = 0; a < 4; ++a)
#pragma unroll
        for (int b = 0; b < 4; ++b)
            acc[a][b] = (f32x4){0.f, 0.f, 0.f, 0.f};

    // ---- prologue: stage A(0) + B(0) -> Bs[0]; drain ----
    STAGE_A(0);
    STAGE_B(0, 0);
    __builtin_amdgcn_sched_barrier(0);
    asm volatile("s_waitcnt vmcnt(0)" ::: "memory");
    __builtin_amdgcn_s_barrier();

    for (int t = 0; t < NT; ++t) {
        const int d = t & 1;

        // B(t+1) staged EARLY into the other B buffer: lands under compute.
        // (Bs[d^1] reads completed at t-1's BAR1.)
        if (t + 1 < NT) STAGE_B(d ^ 1, (t + 1) * BK);

        // ---- compute tile t from As, Bs[d] ----
#pragma unroll
        for (int kk = 0; kk < 2; ++kk) {
            const int kof = (kk * 64 + lhi * 16) ^ swz4;
            short8 af[4], bf[4];
#pragma unroll
            for (int a = 0; a < 4; ++a)
                af[a] = RD((const char*)As + (wr * 64 + a * 16 + l15) * 128 + kof);
#pragma unroll
            for (int b = 0; b < 4; ++b)
                bf[b] = RD((const char*)&Bs[d][0] + (wc * 64 + b * 16 + l15) * 128 + kof);
            __builtin_amdgcn_s_setprio(1);
#pragma unroll
            for (int a = 0; a < 4; ++a)
#pragma unroll
                for (int b = 0; b < 4; ++b)
                    acc[a][b] = __builtin_amdgcn_mfma_f32_16x16x32_bf16(
                        af[a], bf[b], acc[a][b], 0, 0, 0);
            __builtin_amdgcn_s_setprio(0);
        }

        if (t + 1 < NT) {
            __builtin_amdgcn_sched_barrier(0);
            asm volatile("s_waitcnt lgkmcnt(0)" ::: "memory");
            __builtin_amdgcn_s_barrier();       // BAR1: all reads of t done
            STAGE_A((t + 1) * BK);              // only A in the window
            __builtin_amdgcn_sched_barrier(0);
            asm volatile("s_waitcnt vmcnt(0)" ::: "memory");  // B landed long ago
            __builtin_amdgcn_s_barrier();       // BAR2: t+1 visible
        }
    }
#undef STG1
#undef STAGE_A
#undef STAGE_B

    // ---- fused LSTM epilogue (shuffle-free) ----
    const int j0 = ((bn + wc * 64) >> 6) * 16 + l15;
    const float bi  = b_i[j0];
    const float bf_ = b_f[j0];
    const float bg  = b_g[j0];
    const float bo  = b_o[j0];

#pragma unroll
    for (int a = 0; a < 4; ++a) {
        int mbase = bm + wr * 64 + a * 16 + lhi * 4;
#pragma unroll
        for (int r = 0; r < 4; ++r) {
            int m = mbase + r;
            float vi = acc[a][0][r] + bi;
            float vf = acc[a][1][r] + bf_;
            float vg = acc[a][2][r] + bg;
            float vo = acc[a][3][r] + bo;
            float it = sigmoid_(vi);
            float ft = sigmoid_(vf);
            float gt = tanh_(vg);
            float ot = sigmoid_(vo);
            float cp = c_prev[(size_t)m * Hdim + j0];
            float ct = ft * cp + it * gt;
            float ht = ot * tanh_(ct);
            out_h[(size_t)m * Hdim + j0] = ht;
            out_c[(size_t)m * Hdim + j0] = ct;
        }
    }
}

extern "C" void kernel_launch(void* const* d_in, const int* in_sizes, int n_in,
                              void* d_out, int out_size, void* d_ws, size_t ws_size,
                              hipStream_t stream) {
    const float* x_t    = (const float*)d_in[0];
    const float* h_prev = (const float*)d_in[1];
    const float* c_prev = (const float*)d_in[2];
    const float* W_xi   = (const float*)d_in[3];
    const float* W_hi   = (const float*)d_in[4];
    const float* b_i    = (const float*)d_in[5];
    const float* W_xf   = (const float*)d_in[6];
    const float* W_hf   = (const float*)d_in[7];
    const float* b_f    = (const float*)d_in[8];
    const float* W_xg   = (const float*)d_in[9];
    const float* W_hg   = (const float*)d_in[10];
    const float* b_g    = (const float*)d_in[11];
    const float* W_xo   = (const float*)d_in[12];
    const float* W_ho   = (const float*)d_in[13];
    const float* b_o    = (const float*)d_in[14];

    float* out_h = (float*)d_out;
    float* out_c = out_h + (size_t)Mdim * Hdim;

    __hip_bfloat16* Abf = (__hip_bfloat16*)d_ws;
    __hip_bfloat16* Bbf = Abf + (size_t)Mdim * Kdim;

    build_AB<<<8192, 256, 0, stream>>>(x_t, h_prev, W_xi, W_hi, W_xf, W_hf,
                                       W_xg, W_hg, W_xo, W_ho, Abf, Bbf);

    lstm_gemm<<<dim3((Mdim / BM) * (Ndim / BN)), 512, 0, stream>>>(
        Abf, Bbf, c_prev, b_i, b_f, b_g, b_o, out_h, out_c);
}